// Round 1
// baseline (598.107 us; speedup 1.0000x reference)
//
#include <hip/hip_runtime.h>
#include <hip/hip_bf16.h>

// Problem constants (B=2,S=2048,H=1024,E=8,I=2048,topk=2)
#define T_TOKENS 4096
#define H_DIM    1024
#define E_EXP    8
#define I_DIM    2048

typedef short bf16x8 __attribute__((ext_vector_type(8)));
typedef float f32x4  __attribute__((ext_vector_type(4)));

__device__ inline unsigned short f2bf(float f) {
  union { __hip_bfloat16 h; unsigned short u; } c;
  c.h = __float2bfloat16(f);
  return c.u;
}

// ---- cast fp32 -> bf16, same layout, 4 elems/thread ----
__global__ void cast_bf16_kernel(const float* __restrict__ in,
                                 unsigned short* __restrict__ out, int n) {
  int i = (blockIdx.x * blockDim.x + threadIdx.x) * 4;
  if (i >= n) return;
  float4 v = *(const float4*)(in + i);
  ushort4 o;
  o.x = f2bf(v.x); o.y = f2bf(v.y); o.z = f2bf(v.z); o.w = f2bf(v.w);
  *(ushort4*)(out + i) = o;
}

// ---- cast + transpose: in [E][K][N] f32 -> out [E][N][K] bf16 ----
__global__ void cast_transpose_kernel(const float* __restrict__ in,
                                      unsigned short* __restrict__ out,
                                      int K, int N) {
  __shared__ float tile[32][33];
  const float* src = in + (size_t)blockIdx.z * K * N;
  unsigned short* dst = out + (size_t)blockIdx.z * K * N;
  int n0 = blockIdx.x * 32, k0 = blockIdx.y * 32;
  int tx = threadIdx.x, ty = threadIdx.y;  // 32 x 8
#pragma unroll
  for (int i = 0; i < 4; i++) {
    int r = ty + i * 8;
    tile[r][tx] = src[(size_t)(k0 + r) * N + n0 + tx];
  }
  __syncthreads();
#pragma unroll
  for (int i = 0; i < 4; i++) {
    int r = ty + i * 8;
    dst[(size_t)(n0 + r) * K + k0 + tx] = f2bf(tile[tx][r]);
  }
}

// ---- router: 1 wave per token, fp32 logits, top-2 softmax, append to expert lists ----
__global__ void router_kernel(const float* __restrict__ x, const float* __restrict__ Wg,
                              int* __restrict__ counts, int* __restrict__ list_tok,
                              float* __restrict__ list_gate) {
  int t = blockIdx.x;
  int lane = threadIdx.x;
  float acc[8];
#pragma unroll
  for (int e = 0; e < 8; e++) acc[e] = 0.f;
  const float* xr = x + (size_t)t * H_DIM;
  for (int h = lane; h < H_DIM; h += 64) {
    float xv = xr[h];
    const float4* w = (const float4*)(Wg + (size_t)h * 8);
    float4 w0 = w[0], w1 = w[1];
    acc[0] += xv * w0.x; acc[1] += xv * w0.y; acc[2] += xv * w0.z; acc[3] += xv * w0.w;
    acc[4] += xv * w1.x; acc[5] += xv * w1.y; acc[6] += xv * w1.z; acc[7] += xv * w1.w;
  }
#pragma unroll
  for (int off = 32; off > 0; off >>= 1)
#pragma unroll
    for (int e = 0; e < 8; e++) acc[e] += __shfl_xor(acc[e], off, 64);
  if (lane == 0) {
    // top-2, ties -> lower index (matches lax.top_k)
    int e1 = 0; float l1 = acc[0];
    for (int e = 1; e < 8; e++) if (acc[e] > l1) { l1 = acc[e]; e1 = e; }
    int e2 = -1; float l2 = -1e30f;
    for (int e = 0; e < 8; e++) if (e != e1 && acc[e] > l2) { l2 = acc[e]; e2 = e; }
    float g1 = 1.f / (1.f + expf(l2 - l1));  // softmax over [l1,l2], l1 >= l2
    float g2 = 1.f - g1;
    int p1 = atomicAdd(&counts[e1], 1);
    list_tok[e1 * T_TOKENS + p1] = t; list_gate[e1 * T_TOKENS + p1] = g1;
    int p2 = atomicAdd(&counts[e2], 1);
    list_tok[e2 * T_TOKENS + p2] = t; list_gate[e2 * T_TOKENS + p2] = g2;
  }
}

__global__ void prefix_kernel(const int* __restrict__ counts, int* __restrict__ base) {
  if (threadIdx.x == 0) {
    int s = 0;
    for (int e = 0; e < 8; e++) { base[e] = s; s += counts[e]; }
  }
}

// ---- GEMM1: per expert, gathered tokens. 128x64 tile, computes g AND u cols,
//      fused silu(g)*u -> a_buf[slot][I] bf16 ----
__global__ __launch_bounds__(256) void gemm1_kernel(
    const unsigned short* __restrict__ xb,      // [T][H] bf16
    const unsigned short* __restrict__ w_in_t,  // [E][2I=4096][H=1024] bf16 (transposed)
    const int* __restrict__ counts, const int* __restrict__ base,
    const int* __restrict__ list_tok,
    unsigned short* __restrict__ a_buf)         // [2T=8192][I=2048] bf16
{
  int e = blockIdx.z;
  int Ne = counts[e];
  int row0 = blockIdx.y * 128;
  if (row0 >= Ne) return;
  int n0 = blockIdx.x * 64;
  const unsigned short* W = w_in_t + (size_t)e * 4096 * 1024;
  int slot_base = base[e];

  __shared__ unsigned short As[128][32];
  __shared__ unsigned short Bg[64][32];
  __shared__ unsigned short Bu[64][32];
  __shared__ int toks[128];

  int tid = threadIdx.x;
  if (tid < 128) {
    int pos = row0 + tid;
    toks[tid] = list_tok[e * T_TOKENS + (pos < Ne ? pos : 0)];
  }
  __syncthreads();

  // staging addresses (hoisted)
  int sr0 = tid >> 2, sc = (tid & 3) * 8;
  const unsigned short* aptr0 = xb + (size_t)toks[sr0] * H_DIM + sc;
  const unsigned short* aptr1 = xb + (size_t)toks[sr0 + 64] * H_DIM + sc;
  const unsigned short* bgp = W + (size_t)(n0 + sr0) * H_DIM + sc;
  const unsigned short* bup = W + (size_t)(2048 + n0 + sr0) * H_DIM + sc;

  f32x4 accg[4][2] = {};
  f32x4 accu[4][2] = {};

  int lane = tid & 63, wv = tid >> 6;
  int wr = (wv >> 1) * 64, wc = (wv & 1) * 32;
  int lrow = lane & 15, quad = lane >> 4;

  for (int k0 = 0; k0 < H_DIM; k0 += 32) {
    *(uint4*)&As[sr0][sc]      = *(const uint4*)(aptr0 + k0);
    *(uint4*)&As[sr0 + 64][sc] = *(const uint4*)(aptr1 + k0);
    *(uint4*)&Bg[sr0 & 63][sc] = *(const uint4*)(bgp + k0);
    *(uint4*)&Bu[sr0 & 63][sc] = *(const uint4*)(bup + k0);
    __syncthreads();
    bf16x8 af[4], bgf[2], buf2[2];
#pragma unroll
    for (int rr = 0; rr < 4; rr++)
      af[rr] = *(const bf16x8*)&As[wr + rr * 16 + lrow][quad * 8];
#pragma unroll
    for (int cc = 0; cc < 2; cc++) {
      bgf[cc]  = *(const bf16x8*)&Bg[wc + cc * 16 + lrow][quad * 8];
      buf2[cc] = *(const bf16x8*)&Bu[wc + cc * 16 + lrow][quad * 8];
    }
#pragma unroll
    for (int rr = 0; rr < 4; rr++)
#pragma unroll
      for (int cc = 0; cc < 2; cc++) {
        accg[rr][cc] = __builtin_amdgcn_mfma_f32_16x16x32_bf16(af[rr], bgf[cc], accg[rr][cc], 0, 0, 0);
        accu[rr][cc] = __builtin_amdgcn_mfma_f32_16x16x32_bf16(af[rr], buf2[cc], accu[rr][cc], 0, 0, 0);
      }
    __syncthreads();
  }

  // epilogue: a = silu(g)*u, masked store to a_buf
#pragma unroll
  for (int rr = 0; rr < 4; rr++)
#pragma unroll
    for (int cc = 0; cc < 2; cc++)
#pragma unroll
      for (int v = 0; v < 4; v++) {
        int r = wr + rr * 16 + quad * 4 + v;
        int pos = row0 + r;
        if (pos < Ne) {
          int col = n0 + wc + cc * 16 + lrow;
          float g = accg[rr][cc][v], u = accu[rr][cc][v];
          float a = g / (1.f + __expf(-g)) * u;
          a_buf[(size_t)(slot_base + pos) * I_DIM + col] = f2bf(a);
        }
      }
}

// ---- GEMM2: y = a_buf @ W_out^T(e), scatter gate*y into out via atomics ----
__global__ __launch_bounds__(256) void gemm2_kernel(
    const unsigned short* __restrict__ a_buf,    // [8192][2048] bf16
    const unsigned short* __restrict__ w_out_t,  // [E][H=1024][I=2048] bf16 (transposed)
    const int* __restrict__ counts, const int* __restrict__ base,
    const int* __restrict__ list_tok, const float* __restrict__ list_gate,
    float* __restrict__ out)                     // [T][H] fp32
{
  int e = blockIdx.z;
  int Ne = counts[e];
  int row0 = blockIdx.y * 128;
  if (row0 >= Ne) return;
  int n0 = blockIdx.x * 64;
  const unsigned short* W = w_out_t + (size_t)e * 1024 * 2048;
  int slot_base = base[e];

  __shared__ unsigned short As[128][32];
  __shared__ unsigned short Bs[64][32];
  __shared__ int toks[128];
  __shared__ float gts[128];

  int tid = threadIdx.x;
  if (tid < 128) {
    int pos = row0 + tid;
    int cp = pos < Ne ? pos : Ne - 1;
    toks[tid] = list_tok[e * T_TOKENS + cp];
    gts[tid] = list_gate[e * T_TOKENS + cp];
  }
  __syncthreads();

  int sr0 = tid >> 2, sc = (tid & 3) * 8;
  int p0 = row0 + sr0;        int s0 = slot_base + (p0 < Ne ? p0 : Ne - 1);
  int p1 = row0 + sr0 + 64;   int s1 = slot_base + (p1 < Ne ? p1 : Ne - 1);
  const unsigned short* aptr0 = a_buf + (size_t)s0 * I_DIM + sc;
  const unsigned short* aptr1 = a_buf + (size_t)s1 * I_DIM + sc;
  const unsigned short* bptr  = W + (size_t)(n0 + (sr0 & 63)) * I_DIM + sc;

  f32x4 acc[4][2] = {};
  int lane = tid & 63, wv = tid >> 6;
  int wr = (wv >> 1) * 64, wc = (wv & 1) * 32;
  int lrow = lane & 15, quad = lane >> 4;

  for (int k0 = 0; k0 < I_DIM; k0 += 32) {
    *(uint4*)&As[sr0][sc]      = *(const uint4*)(aptr0 + k0);
    *(uint4*)&As[sr0 + 64][sc] = *(const uint4*)(aptr1 + k0);
    *(uint4*)&Bs[sr0 & 63][sc] = *(const uint4*)(bptr + k0);
    __syncthreads();
    bf16x8 af[4], bf[2];
#pragma unroll
    for (int rr = 0; rr < 4; rr++)
      af[rr] = *(const bf16x8*)&As[wr + rr * 16 + lrow][quad * 8];
#pragma unroll
    for (int cc = 0; cc < 2; cc++)
      bf[cc] = *(const bf16x8*)&Bs[wc + cc * 16 + lrow][quad * 8];
#pragma unroll
    for (int rr = 0; rr < 4; rr++)
#pragma unroll
      for (int cc = 0; cc < 2; cc++)
        acc[rr][cc] = __builtin_amdgcn_mfma_f32_16x16x32_bf16(af[rr], bf[cc], acc[rr][cc], 0, 0, 0);
    __syncthreads();
  }

#pragma unroll
  for (int rr = 0; rr < 4; rr++)
#pragma unroll
    for (int cc = 0; cc < 2; cc++)
#pragma unroll
      for (int v = 0; v < 4; v++) {
        int r = wr + rr * 16 + quad * 4 + v;
        int pos = row0 + r;
        if (pos < Ne) {
          int col = n0 + wc + cc * 16 + lrow;
          atomicAdd(&out[(size_t)toks[r] * H_DIM + col], gts[r] * acc[rr][cc][v]);
        }
      }
}

extern "C" void kernel_launch(void* const* d_in, const int* in_sizes, int n_in,
                              void* d_out, int out_size, void* d_ws, size_t ws_size,
                              hipStream_t stream) {
  const float* x     = (const float*)d_in[0];
  const float* Wg    = (const float*)d_in[1];
  const float* W_in  = (const float*)d_in[2];
  const float* W_out = (const float*)d_in[3];
  // d_in[4] = top_k (==2), baked in.

  char* ws = (char*)d_ws;
  size_t off = 0;
  auto alloc = [&](size_t bytes) {
    char* p = ws + off;
    off += (bytes + 255) & ~(size_t)255;
    return p;
  };
  unsigned short* xb      = (unsigned short*)alloc((size_t)T_TOKENS * H_DIM * 2);        // 8 MB
  unsigned short* w_in_t  = (unsigned short*)alloc((size_t)E_EXP * 2 * I_DIM * H_DIM * 2); // 67 MB
  unsigned short* w_out_t = (unsigned short*)alloc((size_t)E_EXP * H_DIM * I_DIM * 2);   // 33.5 MB
  unsigned short* a_buf   = (unsigned short*)alloc((size_t)2 * T_TOKENS * I_DIM * 2);    // 33.5 MB
  int*   counts    = (int*)alloc(E_EXP * 4);
  int*   base      = (int*)alloc(E_EXP * 4);
  int*   list_tok  = (int*)alloc((size_t)E_EXP * T_TOKENS * 4);
  float* list_gate = (float*)alloc((size_t)E_EXP * T_TOKENS * 4);
  if (off > ws_size) return;  // workspace too small -> loud failure, no OOB

  hipMemsetAsync(counts, 0, E_EXP * 4, stream);
  hipMemsetAsync(d_out, 0, (size_t)out_size * 4, stream);

  cast_bf16_kernel<<<(T_TOKENS * H_DIM / 4 + 255) / 256, 256, 0, stream>>>(x, xb, T_TOKENS * H_DIM);
  // W_in [E][K=1024][N=4096] -> [E][4096][1024]
  cast_transpose_kernel<<<dim3(4096 / 32, 1024 / 32, E_EXP), dim3(32, 8), 0, stream>>>(W_in, w_in_t, 1024, 4096);
  // W_out [E][K=2048][N=1024] -> [E][1024][2048]
  cast_transpose_kernel<<<dim3(1024 / 32, 2048 / 32, E_EXP), dim3(32, 8), 0, stream>>>(W_out, w_out_t, 2048, 1024);
  router_kernel<<<T_TOKENS, 64, 0, stream>>>(x, Wg, counts, list_tok, list_gate);
  prefix_kernel<<<1, 1, 0, stream>>>(counts, base);
  gemm1_kernel<<<dim3(I_DIM / 64, T_TOKENS / 128, E_EXP), 256, 0, stream>>>(
      xb, w_in_t, counts, base, list_tok, a_buf);
  gemm2_kernel<<<dim3(H_DIM / 64, T_TOKENS / 128, E_EXP), 256, 0, stream>>>(
      a_buf, w_out_t, counts, base, list_tok, list_gate, (float*)d_out);
}

// Round 2
// 554.415 us; speedup vs baseline: 1.0788x; 1.0788x over previous
//
#include <hip/hip_runtime.h>
#include <hip/hip_bf16.h>

// Problem constants (B=2,S=2048,H=1024,E=8,I=2048,topk=2)
#define T_TOKENS 4096
#define H_DIM    1024
#define E_EXP    8
#define I_DIM    2048

typedef short bf16x8  __attribute__((ext_vector_type(8)));
typedef float f32x16  __attribute__((ext_vector_type(16)));

// XOR swizzle for LDS 16B k-groups (row = LDS tile-local row)
#define SWZ(r) (((r) >> 1) & 3)

__device__ inline unsigned short f2bf(float f) {
  union { __hip_bfloat16 h; unsigned short u; } c;
  c.h = __float2bfloat16(f);
  return c.u;
}

// async global->LDS DMA, 16 B per lane, dest = wave-uniform base + lane*16
__device__ inline void load16_lds(const void* g, void* l) {
  __builtin_amdgcn_global_load_lds(
      (const __attribute__((address_space(1))) unsigned int*)g,
      (__attribute__((address_space(3))) unsigned int*)l, 16, 0, 0);
}

// ---- cast fp32 -> bf16, same layout ----
__global__ void cast_bf16_kernel(const float* __restrict__ in,
                                 unsigned short* __restrict__ out, int n) {
  int i = (blockIdx.x * blockDim.x + threadIdx.x) * 4;
  if (i >= n) return;
  float4 v = *(const float4*)(in + i);
  ushort4 o;
  o.x = f2bf(v.x); o.y = f2bf(v.y); o.z = f2bf(v.z); o.w = f2bf(v.w);
  *(ushort4*)(out + i) = o;
}

// ---- cast + transpose: in [E][K][N] f32 -> out [E][N][K] bf16 ----
// tile: 64 k x 32 n, 256 threads, 16B vectorized output
__global__ void cast_transpose_kernel(const float* __restrict__ in,
                                      unsigned short* __restrict__ out,
                                      int K, int N) {
  __shared__ float tile[64][33];
  const float* src = in + (size_t)blockIdx.z * K * N;
  unsigned short* dst = out + (size_t)blockIdx.z * K * N;
  int n0 = blockIdx.x * 32, k0 = blockIdx.y * 64;
  int tid = threadIdx.x;
#pragma unroll
  for (int r = 0; r < 8; r++) {
    int idx = r * 256 + tid;
    int kk = idx >> 5, nn = idx & 31;
    tile[kk][nn] = src[(size_t)(k0 + kk) * N + n0 + nn];
  }
  __syncthreads();
  int n = tid >> 3, kg = tid & 7;
  __align__(16) unsigned short o[8];
#pragma unroll
  for (int j = 0; j < 8; j++) o[j] = f2bf(tile[kg * 8 + j][n]);
  *(uint4*)&dst[(size_t)(n0 + n) * K + k0 + kg * 8] = *(uint4*)o;
}

// ---- router: 1 wave per token, fp32, top-2 softmax, append to expert lists ----
__global__ void router_kernel(const float* __restrict__ x, const float* __restrict__ Wg,
                              int* __restrict__ counts, int* __restrict__ list_tok,
                              float* __restrict__ list_gate) {
  int t = blockIdx.x;
  int lane = threadIdx.x;
  float acc[8];
#pragma unroll
  for (int e = 0; e < 8; e++) acc[e] = 0.f;
  const float* xr = x + (size_t)t * H_DIM;
  for (int h = lane; h < H_DIM; h += 64) {
    float xv = xr[h];
    const float4* w = (const float4*)(Wg + (size_t)h * 8);
    float4 w0 = w[0], w1 = w[1];
    acc[0] += xv * w0.x; acc[1] += xv * w0.y; acc[2] += xv * w0.z; acc[3] += xv * w0.w;
    acc[4] += xv * w1.x; acc[5] += xv * w1.y; acc[6] += xv * w1.z; acc[7] += xv * w1.w;
  }
#pragma unroll
  for (int off = 32; off > 0; off >>= 1)
#pragma unroll
    for (int e = 0; e < 8; e++) acc[e] += __shfl_xor(acc[e], off, 64);
  if (lane == 0) {
    int e1 = 0; float l1 = acc[0];
    for (int e = 1; e < 8; e++) if (acc[e] > l1) { l1 = acc[e]; e1 = e; }
    int e2 = -1; float l2 = -1e30f;
    for (int e = 0; e < 8; e++) if (e != e1 && acc[e] > l2) { l2 = acc[e]; e2 = e; }
    float g1 = 1.f / (1.f + expf(l2 - l1));
    float g2 = 1.f - g1;
    int p1 = atomicAdd(&counts[e1], 1);
    list_tok[e1 * T_TOKENS + p1] = t; list_gate[e1 * T_TOKENS + p1] = g1;
    int p2 = atomicAdd(&counts[e2], 1);
    list_tok[e2 * T_TOKENS + p2] = t; list_gate[e2 * T_TOKENS + p2] = g2;
  }
}

__global__ void prefix_kernel(const int* __restrict__ counts, int* __restrict__ base) {
  if (threadIdx.x == 0) {
    int s = 0;
    for (int e = 0; e < 8; e++) { base[e] = s; s += counts[e]; }
  }
}

// ---- GEMM1: 128 rows x (64 g-cols + 64 u-cols), 32x32x16 MFMA, DMA staging,
//      swizzled LDS, fused silu(g)*u -> a_buf bf16 ----
__global__ __launch_bounds__(256) void gemm1_kernel(
    const unsigned short* __restrict__ xb,      // [T][1024] bf16
    const unsigned short* __restrict__ w_in_t,  // [E][4096][1024] bf16
    const int* __restrict__ counts, const int* __restrict__ base,
    const int* __restrict__ list_tok,
    unsigned short* __restrict__ a_buf)         // [8192][2048] bf16
{
  int e = blockIdx.z;
  int Ne = counts[e];
  int row0 = blockIdx.y * 128;
  if (row0 >= Ne) return;
  int n0 = blockIdx.x * 64;
  const unsigned short* W = w_in_t + (size_t)e * 4096 * 1024;
  int slot_base = base[e];

  __shared__ __align__(16) unsigned short As[128 * 32];   // 8 KB
  __shared__ __align__(16) unsigned short Bg[64 * 32];    // 4 KB
  __shared__ __align__(16) unsigned short Bu[64 * 32];    // 4 KB
  __shared__ int toks[128];

  int tid = threadIdx.x;
  if (tid < 128) {
    int pos = row0 + tid;
    toks[tid] = list_tok[e * T_TOKENS + (pos < Ne ? pos : 0)];
  }
  __syncthreads();

  // staging sources (swizzle applied by source k-group selection)
  int rA0 = tid >> 2, rA1 = 64 + (tid >> 2);
  int kgA0 = (tid & 3) ^ SWZ(rA0), kgA1 = (tid & 3) ^ SWZ(rA1);
  const unsigned short* srcA0 = xb + (size_t)toks[rA0] * H_DIM + kgA0 * 8;
  const unsigned short* srcA1 = xb + (size_t)toks[rA1] * H_DIM + kgA1 * 8;
  int rB = tid >> 2;
  int kgB = (tid & 3) ^ SWZ(rB);
  const unsigned short* srcBg = W + (size_t)(n0 + rB) * H_DIM + kgB * 8;
  const unsigned short* srcBu = W + (size_t)(2048 + n0 + rB) * H_DIM + kgB * 8;

  int wv = tid >> 6, lane = tid & 63;
  unsigned short* ldsA0 = As + wv * 512;          // wave-uniform bases (x512 ushort = 1KB)
  unsigned short* ldsA1 = As + 2048 + wv * 512;
  unsigned short* ldsBg = Bg + wv * 512;
  unsigned short* ldsBu = Bu + wv * 512;

  int ln31 = lane & 31, lhi = lane >> 5;
  int wr = (wv >> 1) * 64, wc = (wv & 1) * 32;

  f32x16 accg[2] = {}, accu[2] = {};

  for (int k0 = 0; k0 < H_DIM; k0 += 32) {
    load16_lds(srcA0 + k0, ldsA0);
    load16_lds(srcA1 + k0, ldsA1);
    load16_lds(srcBg + k0, ldsBg);
    load16_lds(srcBu + k0, ldsBu);
    __syncthreads();

    bf16x8 af[2][2], bg[2], bu[2];
#pragma unroll
    for (int rb = 0; rb < 2; rb++) {
      int row = wr + rb * 32 + ln31;
#pragma unroll
      for (int ks = 0; ks < 2; ks++) {
        int kg = (ks * 2 + lhi) ^ SWZ(row);
        af[rb][ks] = *(const bf16x8*)&As[row * 32 + kg * 8];
      }
    }
#pragma unroll
    for (int ks = 0; ks < 2; ks++) {
      int n = wc + ln31;
      int kg = (ks * 2 + lhi) ^ SWZ(n);
      bg[ks] = *(const bf16x8*)&Bg[n * 32 + kg * 8];
      bu[ks] = *(const bf16x8*)&Bu[n * 32 + kg * 8];
    }
#pragma unroll
    for (int rb = 0; rb < 2; rb++)
#pragma unroll
      for (int ks = 0; ks < 2; ks++) {
        accg[rb] = __builtin_amdgcn_mfma_f32_32x32x16_bf16(af[rb][ks], bg[ks], accg[rb], 0, 0, 0);
        accu[rb] = __builtin_amdgcn_mfma_f32_32x32x16_bf16(af[rb][ks], bu[ks], accu[rb], 0, 0, 0);
      }
    __syncthreads();
  }

  // epilogue: a = silu(g)*u   (32x32 C/D: col=lane&31, row=(reg&3)+8*(reg>>2)+4*(lane>>5))
  int col = n0 + wc + ln31;
#pragma unroll
  for (int rb = 0; rb < 2; rb++)
#pragma unroll
    for (int reg = 0; reg < 16; reg++) {
      int row_in = wr + rb * 32 + (reg & 3) + 8 * (reg >> 2) + 4 * lhi;
      int pos = row0 + row_in;
      if (pos < Ne) {
        float g = accg[rb][reg], u = accu[rb][reg];
        float a = g / (1.f + __expf(-g)) * u;
        a_buf[(size_t)(slot_base + pos) * I_DIM + col] = f2bf(a);
      }
    }
}

// ---- GEMM2: 128 x 128 tile, K=2048, scatter gate*y via atomicAdd ----
__global__ __launch_bounds__(256) void gemm2_kernel(
    const unsigned short* __restrict__ a_buf,    // [8192][2048] bf16
    const unsigned short* __restrict__ w_out_t,  // [E][1024][2048] bf16
    const int* __restrict__ counts, const int* __restrict__ base,
    const int* __restrict__ list_tok, const float* __restrict__ list_gate,
    float* __restrict__ out)                     // [T][1024] fp32
{
  int e = blockIdx.z;
  int Ne = counts[e];
  int row0 = blockIdx.y * 128;
  if (row0 >= Ne) return;
  int n0 = blockIdx.x * 128;
  const unsigned short* W = w_out_t + (size_t)e * 1024 * 2048;
  int slot_base = base[e];

  __shared__ __align__(16) unsigned short As[128 * 32];   // 8 KB
  __shared__ __align__(16) unsigned short Bs[128 * 32];   // 8 KB
  __shared__ int toks[128];
  __shared__ float gts[128];

  int tid = threadIdx.x;
  if (tid < 128) {
    int pos = row0 + tid;
    int cp = pos < Ne ? pos : Ne - 1;
    toks[tid] = list_tok[e * T_TOKENS + cp];
    gts[tid] = list_gate[e * T_TOKENS + cp];
  }
  __syncthreads();

  int rA0 = tid >> 2, rA1 = 64 + (tid >> 2);
  int kgA0 = (tid & 3) ^ SWZ(rA0), kgA1 = (tid & 3) ^ SWZ(rA1);
  int pA0 = row0 + rA0, pA1 = row0 + rA1;
  int sA0 = slot_base + (pA0 < Ne ? pA0 : Ne - 1);
  int sA1 = slot_base + (pA1 < Ne ? pA1 : Ne - 1);
  const unsigned short* srcA0 = a_buf + (size_t)sA0 * I_DIM + kgA0 * 8;
  const unsigned short* srcA1 = a_buf + (size_t)sA1 * I_DIM + kgA1 * 8;
  const unsigned short* srcB0 = W + (size_t)(n0 + rA0) * I_DIM + kgA0 * 8;
  const unsigned short* srcB1 = W + (size_t)(n0 + rA1) * I_DIM + kgA1 * 8;

  int wv = tid >> 6, lane = tid & 63;
  unsigned short* ldsA0 = As + wv * 512;
  unsigned short* ldsA1 = As + 2048 + wv * 512;
  unsigned short* ldsB0 = Bs + wv * 512;
  unsigned short* ldsB1 = Bs + 2048 + wv * 512;

  int ln31 = lane & 31, lhi = lane >> 5;
  int wr = (wv >> 1) * 64, wc = (wv & 1) * 64;

  f32x16 acc[2][2] = {};

  for (int k0 = 0; k0 < I_DIM; k0 += 32) {
    load16_lds(srcA0 + k0, ldsA0);
    load16_lds(srcA1 + k0, ldsA1);
    load16_lds(srcB0 + k0, ldsB0);
    load16_lds(srcB1 + k0, ldsB1);
    __syncthreads();

    bf16x8 af[2][2], bf[2][2];
#pragma unroll
    for (int rb = 0; rb < 2; rb++) {
      int row = wr + rb * 32 + ln31;
#pragma unroll
      for (int ks = 0; ks < 2; ks++) {
        int kg = (ks * 2 + lhi) ^ SWZ(row);
        af[rb][ks] = *(const bf16x8*)&As[row * 32 + kg * 8];
      }
    }
#pragma unroll
    for (int cb = 0; cb < 2; cb++) {
      int n = wc + cb * 32 + ln31;
#pragma unroll
      for (int ks = 0; ks < 2; ks++) {
        int kg = (ks * 2 + lhi) ^ SWZ(n);
        bf[cb][ks] = *(const bf16x8*)&Bs[n * 32 + kg * 8];
      }
    }
#pragma unroll
    for (int rb = 0; rb < 2; rb++)
#pragma unroll
      for (int cb = 0; cb < 2; cb++)
#pragma unroll
        for (int ks = 0; ks < 2; ks++)
          acc[rb][cb] = __builtin_amdgcn_mfma_f32_32x32x16_bf16(af[rb][ks], bf[cb][ks], acc[rb][cb], 0, 0, 0);
    __syncthreads();
  }

#pragma unroll
  for (int rb = 0; rb < 2; rb++)
#pragma unroll
    for (int cb = 0; cb < 2; cb++) {
      int colb = n0 + wc + cb * 32 + ln31;
#pragma unroll
      for (int reg = 0; reg < 16; reg++) {
        int row_in = wr + rb * 32 + (reg & 3) + 8 * (reg >> 2) + 4 * lhi;
        int pos = row0 + row_in;
        if (pos < Ne)
          atomicAdd(&out[(size_t)toks[row_in] * H_DIM + colb], gts[row_in] * acc[rb][cb][reg]);
      }
    }
}

extern "C" void kernel_launch(void* const* d_in, const int* in_sizes, int n_in,
                              void* d_out, int out_size, void* d_ws, size_t ws_size,
                              hipStream_t stream) {
  const float* x     = (const float*)d_in[0];
  const float* Wg    = (const float*)d_in[1];
  const float* W_in  = (const float*)d_in[2];
  const float* W_out = (const float*)d_in[3];

  char* ws = (char*)d_ws;
  size_t off = 0;
  auto alloc = [&](size_t bytes) {
    char* p = ws + off;
    off += (bytes + 255) & ~(size_t)255;
    return p;
  };
  unsigned short* xb      = (unsigned short*)alloc((size_t)T_TOKENS * H_DIM * 2);
  unsigned short* w_in_t  = (unsigned short*)alloc((size_t)E_EXP * 2 * I_DIM * H_DIM * 2);
  unsigned short* w_out_t = (unsigned short*)alloc((size_t)E_EXP * H_DIM * I_DIM * 2);
  unsigned short* a_buf   = (unsigned short*)alloc((size_t)2 * T_TOKENS * I_DIM * 2);
  int*   counts    = (int*)alloc(E_EXP * 4);
  int*   base      = (int*)alloc(E_EXP * 4);
  int*   list_tok  = (int*)alloc((size_t)E_EXP * T_TOKENS * 4);
  float* list_gate = (float*)alloc((size_t)E_EXP * T_TOKENS * 4);
  if (off > ws_size) return;

  hipMemsetAsync(counts, 0, E_EXP * 4, stream);
  hipMemsetAsync(d_out, 0, (size_t)out_size * 4, stream);

  cast_bf16_kernel<<<(T_TOKENS * H_DIM / 4 + 255) / 256, 256, 0, stream>>>(x, xb, T_TOKENS * H_DIM);
  // W_in [E][1024][4096] -> [E][4096][1024]
  cast_transpose_kernel<<<dim3(4096 / 32, 1024 / 64, E_EXP), 256, 0, stream>>>(W_in, w_in_t, 1024, 4096);
  // W_out [E][2048][1024] -> [E][1024][2048]
  cast_transpose_kernel<<<dim3(1024 / 32, 2048 / 64, E_EXP), 256, 0, stream>>>(W_out, w_out_t, 2048, 1024);
  router_kernel<<<T_TOKENS, 64, 0, stream>>>(x, Wg, counts, list_tok, list_gate);
  prefix_kernel<<<1, 1, 0, stream>>>(counts, base);
  gemm1_kernel<<<dim3(I_DIM / 64, T_TOKENS / 128, E_EXP), 256, 0, stream>>>(
      xb, w_in_t, counts, base, list_tok, a_buf);
  gemm2_kernel<<<dim3(H_DIM / 128, T_TOKENS / 128, E_EXP), 256, 0, stream>>>(
      a_buf, w_out_t, counts, base, list_tok, list_gate, (float*)d_out);
}

// Round 3
// 540.833 us; speedup vs baseline: 1.1059x; 1.0251x over previous
//
#include <hip/hip_runtime.h>
#include <hip/hip_bf16.h>

// Problem constants (B=2,S=2048,H=1024,E=8,I=2048,topk=2)
#define T_TOKENS 4096
#define H_DIM    1024
#define E_EXP    8
#define I_DIM    2048

typedef short bf16x8 __attribute__((ext_vector_type(8)));
typedef float f32x4  __attribute__((ext_vector_type(4)));

// XOR swizzle of 16B k-group slots vs LDS row (row stride 64B)
#define SWZ(r) (((r) >> 1) & 3)

__device__ inline unsigned short f2bf(float f) {
  union { __hip_bfloat16 h; unsigned short u; } c;
  c.h = __float2bfloat16(f);
  return c.u;
}
__device__ inline float bf2f(unsigned short u) {
  union { unsigned int i; float f; } c;
  c.i = (unsigned int)u << 16;
  return c.f;
}

// async global->LDS DMA, 16 B/lane, dest = wave-uniform base + lane*16
__device__ inline void load16_lds(const void* g, void* l) {
  __builtin_amdgcn_global_load_lds(
      (const __attribute__((address_space(1))) unsigned int*)g,
      (__attribute__((address_space(3))) unsigned int*)l, 16, 0, 0);
}

// ---- cast fp32 -> bf16 ----
__global__ void cast_bf16_kernel(const float* __restrict__ in,
                                 unsigned short* __restrict__ out, int n) {
  int i = (blockIdx.x * blockDim.x + threadIdx.x) * 4;
  if (i >= n) return;
  float4 v = *(const float4*)(in + i);
  ushort4 o;
  o.x = f2bf(v.x); o.y = f2bf(v.y); o.z = f2bf(v.z); o.w = f2bf(v.w);
  *(ushort4*)(out + i) = o;
}

// ---- cast + transpose: [E][K][N] f32 -> [E][N][K] bf16 ----
__global__ void cast_transpose_kernel(const float* __restrict__ in,
                                      unsigned short* __restrict__ out,
                                      int K, int N) {
  __shared__ float tile[64][33];
  const float* src = in + (size_t)blockIdx.z * K * N;
  unsigned short* dst = out + (size_t)blockIdx.z * K * N;
  int n0 = blockIdx.x * 32, k0 = blockIdx.y * 64;
  int tid = threadIdx.x;
#pragma unroll
  for (int r = 0; r < 8; r++) {
    int idx = r * 256 + tid;
    int kk = idx >> 5, nn = idx & 31;
    tile[kk][nn] = src[(size_t)(k0 + kk) * N + n0 + nn];
  }
  __syncthreads();
  int n = tid >> 3, kg = tid & 7;
  __align__(16) unsigned short o[8];
#pragma unroll
  for (int j = 0; j < 8; j++) o[j] = f2bf(tile[kg * 8 + j][n]);
  *(uint4*)&dst[(size_t)(n0 + n) * K + k0 + kg * 8] = *(uint4*)o;
}

// ---- router: fp32 logits, top-2 softmax, expert lists + per-token slot codes ----
__global__ void router_kernel(const float* __restrict__ x, const float* __restrict__ Wg,
                              int* __restrict__ counts, int* __restrict__ list_tok,
                              float* __restrict__ list_gate, int* __restrict__ tok_codes) {
  int t = blockIdx.x;
  int lane = threadIdx.x;
  float acc[8];
#pragma unroll
  for (int e = 0; e < 8; e++) acc[e] = 0.f;
  const float* xr = x + (size_t)t * H_DIM;
  for (int h = lane; h < H_DIM; h += 64) {
    float xv = xr[h];
    const float4* w = (const float4*)(Wg + (size_t)h * 8);
    float4 w0 = w[0], w1 = w[1];
    acc[0] += xv * w0.x; acc[1] += xv * w0.y; acc[2] += xv * w0.z; acc[3] += xv * w0.w;
    acc[4] += xv * w1.x; acc[5] += xv * w1.y; acc[6] += xv * w1.z; acc[7] += xv * w1.w;
  }
#pragma unroll
  for (int off = 32; off > 0; off >>= 1)
#pragma unroll
    for (int e = 0; e < 8; e++) acc[e] += __shfl_xor(acc[e], off, 64);
  if (lane == 0) {
    int e1 = 0; float l1 = acc[0];
    for (int e = 1; e < 8; e++) if (acc[e] > l1) { l1 = acc[e]; e1 = e; }
    int e2 = -1; float l2 = -1e30f;
    for (int e = 0; e < 8; e++) if (e != e1 && acc[e] > l2) { l2 = acc[e]; e2 = e; }
    float g1 = 1.f / (1.f + expf(l2 - l1));
    float g2 = 1.f - g1;
    int p1 = atomicAdd(&counts[e1], 1);
    list_tok[e1 * T_TOKENS + p1] = t; list_gate[e1 * T_TOKENS + p1] = g1;
    int p2 = atomicAdd(&counts[e2], 1);
    list_tok[e2 * T_TOKENS + p2] = t; list_gate[e2 * T_TOKENS + p2] = g2;
    tok_codes[2 * t]     = e1 * T_TOKENS + p1;
    tok_codes[2 * t + 1] = e2 * T_TOKENS + p2;
  }
}

__global__ void prefix_kernel(const int* __restrict__ counts, int* __restrict__ base) {
  if (threadIdx.x == 0) {
    int s = 0;
    for (int e = 0; e < 8; e++) { base[e] = s; s += counts[e]; }
  }
}

// ---- GEMM1: m97 structure. Block = 128 rows x 64 i-cols (B-tile = 128 rows of
//      interleaved g/u groups). 4 waves, each 64r x 32c(g)+32c(u), 16 MFMA
//      16x16x32 : 8 ds_read_b128 per K-iter. Fused silu(g)*u -> a_buf bf16 ----
__global__ __launch_bounds__(256) void gemm1_kernel(
    const unsigned short* __restrict__ xb,      // [T][1024] bf16
    const unsigned short* __restrict__ w_in_t,  // [E][4096][1024] bf16
    const int* __restrict__ counts, const int* __restrict__ base,
    const int* __restrict__ list_tok,
    unsigned short* __restrict__ a_buf)         // [8192][2048] bf16
{
  int e = blockIdx.z;
  int Ne = counts[e];
  int row0 = blockIdx.y * 128;
  if (row0 >= Ne) return;
  int ib = blockIdx.x * 64;                     // i-col base
  const unsigned short* W = w_in_t + (size_t)e * 4096 * 1024;
  int slot_base = base[e];

  __shared__ __align__(16) unsigned short As[128 * 32];   // 8 KB
  __shared__ __align__(16) unsigned short Bs[128 * 32];   // 8 KB
  __shared__ int toks[128];

  int tid = threadIdx.x;
  if (tid < 128) {
    int pos = row0 + tid;
    toks[tid] = list_tok[e * T_TOKENS + (pos < Ne ? pos : 0)];
  }
  __syncthreads();

  int wv = tid >> 6, lane = tid & 63;

  // staging: wave wv stages A rows [32wv,32wv+32) and B rows [32wv,32wv+32),
  // each as 2 DMAs of 16 rows (1 KB). lane l -> local row l>>2, phys kg slot l&3,
  // source kg = (l&3) ^ SWZ(row).
  const unsigned short* srcA[2];
  const unsigned short* srcB[2];
  unsigned short* ldsA[2];
  unsigned short* ldsB[2];
#pragma unroll
  for (int d = 0; d < 2; d++) {
    int r = 32 * wv + 16 * d + (lane >> 2);        // tile-local row 0..127
    int kg = (lane & 3) ^ SWZ(r);
    srcA[d] = xb + (size_t)toks[r] * H_DIM + kg * 8;
    // B-tile row r -> W row: c=r>>6 (wave col-half), q=(r>>4)&3, rr=r&15
    int c = r >> 6, q = (r >> 4) & 3, rr = r & 15;
    int wrow = (q & 1) * 2048 + ib + 32 * c + (q >> 1) * 16 + rr;
    srcB[d] = W + (size_t)wrow * H_DIM + kg * 8;
    ldsA[d] = As + (32 * wv + 16 * d) * 32;
    ldsB[d] = Bs + (32 * wv + 16 * d) * 32;
  }

  int rh = wv >> 1, ch = wv & 1;
  int l15 = lane & 15, quad = lane >> 4;

  f32x4 acc[4][4] = {};

  for (int k0 = 0; k0 < H_DIM; k0 += 32) {
    load16_lds(srcA[0] + k0, ldsA[0]);
    load16_lds(srcA[1] + k0, ldsA[1]);
    load16_lds(srcB[0] + k0, ldsB[0]);
    load16_lds(srcB[1] + k0, ldsB[1]);
    __syncthreads();

    bf16x8 af[4], bf[4];
#pragma unroll
    for (int rb = 0; rb < 4; rb++) {
      int row = rh * 64 + rb * 16 + l15;
      int kg = quad ^ SWZ(row);
      af[rb] = *(const bf16x8*)&As[row * 32 + kg * 8];
    }
#pragma unroll
    for (int cb = 0; cb < 4; cb++) {
      int brow = ch * 64 + cb * 16 + l15;
      int kg = quad ^ SWZ(brow);
      bf[cb] = *(const bf16x8*)&Bs[brow * 32 + kg * 8];
    }
#pragma unroll
    for (int rb = 0; rb < 4; rb++)
#pragma unroll
      for (int cb = 0; cb < 4; cb++)
        acc[rb][cb] = __builtin_amdgcn_mfma_f32_16x16x32_bf16(af[rb], bf[cb], acc[rb][cb], 0, 0, 0);
    __syncthreads();
  }

  // epilogue: B col-blocks alternate g,u,g,u (16-wide). Pair (2cp, 2cp+1).
#pragma unroll
  for (int rb = 0; rb < 4; rb++)
#pragma unroll
    for (int cp = 0; cp < 2; cp++) {
      int icol = ib + 32 * ch + cp * 16 + l15;
#pragma unroll
      for (int v = 0; v < 4; v++) {
        int row = rh * 64 + rb * 16 + quad * 4 + v;
        int pos = row0 + row;
        if (pos < Ne) {
          float g = acc[rb][2 * cp][v], u = acc[rb][2 * cp + 1][v];
          float a = g / (1.f + __expf(-g)) * u;
          a_buf[(size_t)(slot_base + pos) * I_DIM + icol] = f2bf(a);
        }
      }
    }
}

// ---- GEMM2: m97 structure 128x128, gated bf16 y into y_buf (no atomics) ----
__global__ __launch_bounds__(256) void gemm2_kernel(
    const unsigned short* __restrict__ a_buf,    // [8192][2048] bf16
    const unsigned short* __restrict__ w_out_t,  // [E][1024][2048] bf16
    const int* __restrict__ counts, const int* __restrict__ base,
    const float* __restrict__ list_gate,
    unsigned short* __restrict__ y_buf)          // [8192][1024] bf16
{
  int e = blockIdx.z;
  int Ne = counts[e];
  int row0 = blockIdx.y * 128;
  if (row0 >= Ne) return;
  int hb = blockIdx.x * 128;
  const unsigned short* W = w_out_t + (size_t)e * 1024 * 2048;
  int slot_base = base[e];

  __shared__ __align__(16) unsigned short As[128 * 32];   // 8 KB
  __shared__ __align__(16) unsigned short Bs[128 * 32];   // 8 KB
  __shared__ float gts[128];

  int tid = threadIdx.x;
  if (tid < 128) {
    int pos = row0 + tid;
    gts[tid] = list_gate[e * T_TOKENS + (pos < Ne ? pos : Ne - 1)];
  }

  int wv = tid >> 6, lane = tid & 63;
  const unsigned short* srcA[2];
  const unsigned short* srcB[2];
  unsigned short* ldsA[2];
  unsigned short* ldsB[2];
#pragma unroll
  for (int d = 0; d < 2; d++) {
    int r = 32 * wv + 16 * d + (lane >> 2);
    int kg = (lane & 3) ^ SWZ(r);
    int pos = row0 + r;
    int slot = slot_base + (pos < Ne ? pos : Ne - 1);
    srcA[d] = a_buf + (size_t)slot * I_DIM + kg * 8;
    srcB[d] = W + (size_t)(hb + r) * I_DIM + kg * 8;
    ldsA[d] = As + (32 * wv + 16 * d) * 32;
    ldsB[d] = Bs + (32 * wv + 16 * d) * 32;
  }

  int rh = wv >> 1, ch = wv & 1;
  int l15 = lane & 15, quad = lane >> 4;

  f32x4 acc[4][4] = {};

  for (int k0 = 0; k0 < I_DIM; k0 += 32) {
    load16_lds(srcA[0] + k0, ldsA[0]);
    load16_lds(srcA[1] + k0, ldsA[1]);
    load16_lds(srcB[0] + k0, ldsB[0]);
    load16_lds(srcB[1] + k0, ldsB[1]);
    __syncthreads();

    bf16x8 af[4], bf[4];
#pragma unroll
    for (int rb = 0; rb < 4; rb++) {
      int row = rh * 64 + rb * 16 + l15;
      int kg = quad ^ SWZ(row);
      af[rb] = *(const bf16x8*)&As[row * 32 + kg * 8];
    }
#pragma unroll
    for (int cb = 0; cb < 4; cb++) {
      int brow = ch * 64 + cb * 16 + l15;
      int kg = quad ^ SWZ(brow);
      bf[cb] = *(const bf16x8*)&Bs[brow * 32 + kg * 8];
    }
#pragma unroll
    for (int rb = 0; rb < 4; rb++)
#pragma unroll
      for (int cb = 0; cb < 4; cb++)
        acc[rb][cb] = __builtin_amdgcn_mfma_f32_16x16x32_bf16(af[rb], bf[cb], acc[rb][cb], 0, 0, 0);
    __syncthreads();
  }

#pragma unroll
  for (int rb = 0; rb < 4; rb++)
#pragma unroll
    for (int cb = 0; cb < 4; cb++) {
      int col = hb + ch * 64 + cb * 16 + l15;
#pragma unroll
      for (int v = 0; v < 4; v++) {
        int row = rh * 64 + rb * 16 + quad * 4 + v;
        int pos = row0 + row;
        if (pos < Ne)
          y_buf[(size_t)(slot_base + pos) * H_DIM + col] = f2bf(gts[row] * acc[rb][cb][v]);
      }
    }
}

// ---- combine: out[t] = y[slot1] + y[slot2] (gates pre-applied) ----
__global__ void combine_kernel(const unsigned short* __restrict__ y_buf,
                               const int* __restrict__ tok_codes,
                               const int* __restrict__ base,
                               float* __restrict__ out) {
  int t = blockIdx.x;
  int c0 = tok_codes[2 * t], c1 = tok_codes[2 * t + 1];
  int s0 = base[c0 / T_TOKENS] + (c0 % T_TOKENS);
  int s1 = base[c1 / T_TOKENS] + (c1 % T_TOKENS);
  int h = threadIdx.x * 4;
  ushort4 a = *(const ushort4*)&y_buf[(size_t)s0 * H_DIM + h];
  ushort4 b = *(const ushort4*)&y_buf[(size_t)s1 * H_DIM + h];
  float4 o;
  o.x = bf2f(a.x) + bf2f(b.x);
  o.y = bf2f(a.y) + bf2f(b.y);
  o.z = bf2f(a.z) + bf2f(b.z);
  o.w = bf2f(a.w) + bf2f(b.w);
  *(float4*)&out[(size_t)t * H_DIM + h] = o;
}

extern "C" void kernel_launch(void* const* d_in, const int* in_sizes, int n_in,
                              void* d_out, int out_size, void* d_ws, size_t ws_size,
                              hipStream_t stream) {
  const float* x     = (const float*)d_in[0];
  const float* Wg    = (const float*)d_in[1];
  const float* W_in  = (const float*)d_in[2];
  const float* W_out = (const float*)d_in[3];

  char* ws = (char*)d_ws;
  size_t off = 0;
  auto alloc = [&](size_t bytes) {
    char* p = ws + off;
    off += (bytes + 255) & ~(size_t)255;
    return p;
  };
  unsigned short* xb      = (unsigned short*)alloc((size_t)T_TOKENS * H_DIM * 2);
  unsigned short* w_in_t  = (unsigned short*)alloc((size_t)E_EXP * 2 * I_DIM * H_DIM * 2);
  unsigned short* w_out_t = (unsigned short*)alloc((size_t)E_EXP * H_DIM * I_DIM * 2);
  unsigned short* a_buf   = (unsigned short*)alloc((size_t)2 * T_TOKENS * I_DIM * 2);
  int*   counts    = (int*)alloc(E_EXP * 4);
  int*   base      = (int*)alloc(E_EXP * 4);
  int*   list_tok  = (int*)alloc((size_t)E_EXP * T_TOKENS * 4);
  float* list_gate = (float*)alloc((size_t)E_EXP * T_TOKENS * 4);
  int*   tok_codes = (int*)alloc((size_t)2 * T_TOKENS * 4);
  if (off > ws_size) return;

  // y_buf aliases w_in_t (dead after gemm1): 8192*1024*2 = 16.8 MB <= 67 MB
  unsigned short* y_buf = w_in_t;

  hipMemsetAsync(counts, 0, E_EXP * 4, stream);

  cast_bf16_kernel<<<(T_TOKENS * H_DIM / 4 + 255) / 256, 256, 0, stream>>>(x, xb, T_TOKENS * H_DIM);
  // W_in [E][1024][4096] -> [E][4096][1024]
  cast_transpose_kernel<<<dim3(4096 / 32, 1024 / 64, E_EXP), 256, 0, stream>>>(W_in, w_in_t, 1024, 4096);
  // W_out [E][2048][1024] -> [E][1024][2048]
  cast_transpose_kernel<<<dim3(1024 / 32, 2048 / 64, E_EXP), 256, 0, stream>>>(W_out, w_out_t, 2048, 1024);
  router_kernel<<<T_TOKENS, 64, 0, stream>>>(x, Wg, counts, list_tok, list_gate, tok_codes);
  prefix_kernel<<<1, 1, 0, stream>>>(counts, base);
  gemm1_kernel<<<dim3(I_DIM / 64, T_TOKENS / 128, E_EXP), 256, 0, stream>>>(
      xb, w_in_t, counts, base, list_tok, a_buf);
  gemm2_kernel<<<dim3(H_DIM / 128, T_TOKENS / 128, E_EXP), 256, 0, stream>>>(
      a_buf, w_out_t, counts, base, list_gate, y_buf);
  combine_kernel<<<T_TOKENS, 256, 0, stream>>>(y_buf, tok_codes, base, (float*)d_out);
}